// Round 1
// baseline (820.870 us; speedup 1.0000x reference)
//
#include <hip/hip_runtime.h>

#define NB      16384
#define QS      1204
#define FD      7
#define ROWF    (QS * FD)     // 8428 floats per batch row
#define ROWF4   (ROWF / 4)    // 2107 float4s (8428 % 4 == 0)
#define NCH     120
#define NOFF    5
#define WINSZ   10
#define CATN    600
#define H1N     128
#define H2N     32
#define OUTN    2
#define G       8             // batch rows per block
#define NTHR    256

__global__ __launch_bounds__(NTHR) void fused_struct3(
    const float* __restrict__ x,
    const float* __restrict__ w_step,
    const float* __restrict__ b_step,
    const float* __restrict__ wA,
    const float* __restrict__ bA,
    const float* __restrict__ wB,
    const float* __restrict__ bB,
    const float* __restrict__ wC,
    const float* __restrict__ bC,
    float* __restrict__ out)
{
    __shared__ __align__(16) float rowbuf[ROWF];      // 33712 B
    __shared__ float orow[QS];                        //  4816 B
    __shared__ __align__(16) float cat_s[G][CATN];    // 19200 B
    __shared__ __align__(16) float h1_s[G][H1N];      //  4096 B
    __shared__ float h2_s[G][H2N];                    //  1024 B
    // total 62848 B -> 2 blocks/CU

    const int t  = threadIdx.x;
    const int b0 = blockIdx.x * G;

    const float w0 = w_step[0], w1 = w_step[1], w2 = w_step[2], w3 = w_step[3],
                w4 = w_step[4], w5 = w_step[5], w6 = w_step[6];
    const float bs = b_step[0];

    // ---------- Phase 1: per-row dot + windowed max -> cat_s ----------
    for (int g = 0; g < G; ++g) {
        const float4* src = (const float4*)(x + (size_t)(b0 + g) * ROWF);
        float4* dst = (float4*)rowbuf;
        #pragma unroll
        for (int i = 0; i < 9; ++i) {
            int idx = t + i * NTHR;
            if (idx < ROWF4) dst[idx] = src[idx];
        }
        __syncthreads();

        for (int q = t; q < QS; q += NTHR) {
            const float* p = rowbuf + q * FD;
            float s = fmaf(p[0], w0, bs);
            s = fmaf(p[1], w1, s);
            s = fmaf(p[2], w2, s);
            s = fmaf(p[3], w3, s);
            s = fmaf(p[4], w4, s);
            s = fmaf(p[5], w5, s);
            s = fmaf(p[6], w6, s);
            orow[q] = s;
        }
        __syncthreads();

        for (int j = t; j < CATN; j += NTHR) {
            int ci = j / NOFF;
            int o  = j - ci * NOFF;
            int st = ci * WINSZ + o;
            float m = orow[st];
            #pragma unroll
            for (int w = 1; w < WINSZ; ++w) m = fmaxf(m, orow[st + w]);
            cat_s[g][j] = m;
        }
        __syncthreads();
    }

    // ---------- Phase 2: h1 = relu(cat @ wA + bA) ----------
    {
        const int n  = t & (H1N - 1);        // 0..127
        const int g0 = (t >> 7) << 2;        // 0 or 4 (4 rows per thread)
        float acc0 = 0.f, acc1 = 0.f, acc2 = 0.f, acc3 = 0.f;
        for (int k = 0; k < CATN; k += 4) {
            const float4 c0 = *(const float4*)&cat_s[g0 + 0][k];
            const float4 c1 = *(const float4*)&cat_s[g0 + 1][k];
            const float4 c2 = *(const float4*)&cat_s[g0 + 2][k];
            const float4 c3 = *(const float4*)&cat_s[g0 + 3][k];
            const float a0 = wA[(k + 0) * H1N + n];
            const float a1 = wA[(k + 1) * H1N + n];
            const float a2 = wA[(k + 2) * H1N + n];
            const float a3 = wA[(k + 3) * H1N + n];
            acc0 = fmaf(c0.x, a0, acc0); acc0 = fmaf(c0.y, a1, acc0);
            acc0 = fmaf(c0.z, a2, acc0); acc0 = fmaf(c0.w, a3, acc0);
            acc1 = fmaf(c1.x, a0, acc1); acc1 = fmaf(c1.y, a1, acc1);
            acc1 = fmaf(c1.z, a2, acc1); acc1 = fmaf(c1.w, a3, acc1);
            acc2 = fmaf(c2.x, a0, acc2); acc2 = fmaf(c2.y, a1, acc2);
            acc2 = fmaf(c2.z, a2, acc2); acc2 = fmaf(c2.w, a3, acc2);
            acc3 = fmaf(c3.x, a0, acc3); acc3 = fmaf(c3.y, a1, acc3);
            acc3 = fmaf(c3.z, a2, acc3); acc3 = fmaf(c3.w, a3, acc3);
        }
        const float bias = bA[n];
        h1_s[g0 + 0][n] = fmaxf(acc0 + bias, 0.f);
        h1_s[g0 + 1][n] = fmaxf(acc1 + bias, 0.f);
        h1_s[g0 + 2][n] = fmaxf(acc2 + bias, 0.f);
        h1_s[g0 + 3][n] = fmaxf(acc3 + bias, 0.f);
    }
    __syncthreads();

    // ---------- Phase 3: h2 = relu(h1 @ wB + bB) ----------
    {
        const int g  = t >> 5;               // 0..7
        const int n2 = t & 31;               // 0..31
        float acc = bB[n2];
        #pragma unroll 4
        for (int k = 0; k < H1N; ++k)
            acc = fmaf(h1_s[g][k], wB[k * H2N + n2], acc);
        h2_s[g][n2] = fmaxf(acc, 0.f);
    }
    __syncthreads();

    // ---------- Phase 4: out = h2 @ wC + bC ----------
    if (t < G * OUTN) {
        const int g = t >> 1;
        const int c = t & 1;
        float acc = bC[c];
        #pragma unroll
        for (int k = 0; k < H2N; ++k)
            acc = fmaf(h2_s[g][k], wC[k * OUTN + c], acc);
        out[(size_t)(b0 + g) * OUTN + c] = acc;
    }
}

extern "C" void kernel_launch(void* const* d_in, const int* in_sizes, int n_in,
                              void* d_out, int out_size, void* d_ws, size_t ws_size,
                              hipStream_t stream) {
    const float* x      = (const float*)d_in[0];
    const float* w_step = (const float*)d_in[1];
    const float* b_step = (const float*)d_in[2];
    const float* wA     = (const float*)d_in[3];
    const float* bA     = (const float*)d_in[4];
    const float* wB     = (const float*)d_in[5];
    const float* bB     = (const float*)d_in[6];
    const float* wC     = (const float*)d_in[7];
    const float* bC     = (const float*)d_in[8];
    float* out = (float*)d_out;

    dim3 grid(NB / G);   // 2048 blocks
    fused_struct3<<<grid, NTHR, 0, stream>>>(
        x, w_step, b_step, wA, bA, wB, bB, wC, bC, out);
}